// Round 2
// baseline (165.174 us; speedup 1.0000x reference)
//
#include <hip/hip_runtime.h>
#include <math.h>

#define S_LEN  4096
#define NCH    64
#define TILE_S 64
#define RPT    8           // s-rows per thread
#define TY     8           // 512 threads = 8 waves
#define HALO_L 31
#define WLEN   (61 + RPT)  // 69 window rows per thread
#define PRE    20          // preloaded window depth (~13-step issue-to-use slack)

// 106 fused filter taps, computed on HOST (fp64, bit-matching numpy's index
// math — validated earlier rounds, absmax 1.56e-2 vs 1.03e-1 threshold) and
// passed BY VALUE -> kernarg segment -> scalar s_load in kernel.
struct WtArgs { float w6[62]; float w3[32]; float w1[12]; };

// ---------------------------------------------------------------------------
// Round-5: kill the LDS stage. Round-1 post-mortem: doubling occupancy
// (4->8 waves/SIMD) changed NOTHING (134->137us) -> kernel is NOT
// latency/occupancy-bound; the invariant across both versions is the
// bulk-synchronous LDS staging (stage burst -> barrier drain -> LDS-fed
// compute -> store burst). Input is 33.6MB = L2/L3-resident; LDS is a pure
// middleman (guide common-mistake #7). This version reads the sliding
// window DIRECTLY from global: lane c reads x[row][c] -> 256B/wave
// coalesced, L2-served; register-level sliding-window reuse unchanged; no
// barrier, no LDS, no phase bursts. Interior blocks (sx 1..62) take a
// branch-free instantiation; edge blocks take wave-uniform-guarded loads.
// All indices remain compile-time via template recursion (round-3 lesson:
// dynamic indexing -> scratch allocas).
// ---------------------------------------------------------------------------

template <int T, int R>
struct FmaR {
  static __device__ __forceinline__ void run(const WtArgs& W, const float (&win)[WLEN],
                                             float (&a6)[RPT], float (&a3)[RPT],
                                             float (&a1)[RPT]) {
    a6[R] = fmaf(W.w6[T], win[T + R], a6[R]);
    if constexpr (T >= 15 && T <= 46) a3[R] = fmaf(W.w3[T - 15], win[T + R], a3[R]);
    if constexpr (T >= 25 && T <= 36) a1[R] = fmaf(W.w1[T - 25], win[T + R], a1[R]);
    FmaR<T, R + 1>::run(W, win, a6, a3, a1);
  }
};
template <int T>
struct FmaR<T, RPT> {
  static __device__ __forceinline__ void run(const WtArgs&, const float (&)[WLEN],
                                             float (&)[RPT], float (&)[RPT], float (&)[RPT]) {}
};

// Guarded/unguarded window load: row index (rowbase + K) is wave-uniform
// (rowbase = s0 - 31 + ty*8) -> guard compiles to scalar cmp + branch, no
// lane divergence.
template <int K, bool G>
struct Pre {
  static __device__ __forceinline__ void run(const float* __restrict__ col, int rowbase,
                                             float (&win)[WLEN]) {
    if constexpr (G) {
      float v = 0.f;
      if ((unsigned)(rowbase + K) < (unsigned)S_LEN) v = col[K * NCH];
      win[K] = v;
    } else {
      win[K] = col[K * NCH];
    }
    Pre<K + 1, G>::run(col, rowbase, win);
  }
};
template <bool G>
struct Pre<PRE, G> {
  static __device__ __forceinline__ void run(const float* __restrict__, int, float (&)[WLEN]) {}
};

template <int T, bool G>
struct Step {
  static __device__ __forceinline__ void run(const float* __restrict__ col, int rowbase,
                                             const WtArgs& W, float (&win)[WLEN],
                                             float (&a6)[RPT], float (&a3)[RPT],
                                             float (&a1)[RPT]) {
    if constexpr (T + PRE < WLEN) {
      if constexpr (G) {
        float v = 0.f;
        if ((unsigned)(rowbase + T + PRE) < (unsigned)S_LEN) v = col[(T + PRE) * NCH];
        win[T + PRE] = v;
      } else {
        win[T + PRE] = col[(T + PRE) * NCH];
      }
    }
    FmaR<T, 0>::run(W, win, a6, a3, a1);
    Step<T + 1, G>::run(col, rowbase, W, win, a6, a3, a1);
  }
};
template <bool G>
struct Step<62, G> {
  static __device__ __forceinline__ void run(const float* __restrict__, int, const WtArgs&,
                                             float (&)[WLEN], float (&)[RPT],
                                             float (&)[RPT], float (&)[RPT]) {}
};

template <int R>
struct Store {
  static __device__ __forceinline__ void run(float* __restrict__ o1, float* __restrict__ o3,
                                             float* __restrict__ o6, const float (&a6)[RPT],
                                             const float (&a3)[RPT], const float (&a1)[RPT]) {
    o1[(size_t)R * NCH] = a1[R];
    o3[(size_t)R * NCH] = a3[R];
    o6[(size_t)R * NCH] = a6[R];
    Store<R + 1>::run(o1, o3, o6, a6, a3, a1);
  }
};
template <>
struct Store<RPT> {
  static __device__ __forceinline__ void run(float* __restrict__, float* __restrict__,
                                             float* __restrict__, const float (&)[RPT],
                                             const float (&)[RPT], const float (&)[RPT]) {}
};

template <int R>
struct Zero {
  static __device__ __forceinline__ void run(float (&a6)[RPT], float (&a3)[RPT], float (&a1)[RPT]) {
    a6[R] = 0.f; a3[R] = 0.f; a1[R] = 0.f;
    Zero<R + 1>::run(a6, a3, a1);
  }
};
template <>
struct Zero<RPT> {
  static __device__ __forceinline__ void run(float (&)[RPT], float (&)[RPT], float (&)[RPT]) {}
};

__global__ __launch_bounds__(512, 6)
void cwt_main(const float* __restrict__ x, float* __restrict__ out, const WtArgs W) {
  const int c   = threadIdx.x;        // 0..63 (lane = channel)
  const int ty  = threadIdx.y;        // 0..7 (wave)

  // Bijective XCD swizzle (2048 % 8 == 0): logical ids 256k..256k+255
  // (consecutive s-tiles) land on XCD k -> halo rows re-hit that XCD's L2.
  const int hw  = blockIdx.x;                 // 0..2047
  const int wg  = ((hw & 7) << 8) + (hw >> 3);
  const int sx  = wg & 63;                    // 64 s-tiles (fastest within XCD)
  const int b   = wg >> 6;                    // 32 batches
  const int s0  = sx * TILE_S;

  const float* xb = x + (size_t)b * S_LEN * NCH;
  const int rowbase = s0 - HALO_L + ty * RPT;              // wave-uniform
  const float* col  = xb + (ptrdiff_t)rowbase * NCH + c;   // lane c = channel c

  float win[WLEN];
  float a6[RPT], a3[RPT], a1[RPT];
  Zero<0>::run(a6, a3, a1);

  if (sx >= 1 && sx <= 62) {               // interior: rows [33..4061] all valid
    Pre<0, false>::run(col, rowbase, win);
    Step<0, false>::run(col, rowbase, W, win, a6, a3, a1);
  } else {                                  // edge tiles: wave-uniform guards
    Pre<0, true>::run(col, rowbase, win);
    Step<0, true>::run(col, rowbase, W, win, a6, a3, a1);
  }

  // ---- stores: 64 lanes x 4 B contiguous per row; planes: 0=s1, 1=s3, 2=s6
  const int srow = s0 + ty * RPT;
  float* o1 = out + (((size_t)b * 3 + 0) * S_LEN + srow) * NCH + c;
  float* o3 = out + (((size_t)b * 3 + 1) * S_LEN + srow) * NCH + c;
  float* o6 = out + (((size_t)b * 3 + 2) * S_LEN + srow) * NCH + c;
  Store<0>::run(o1, o3, o6, a6, a3, a1);
}

// ---------------------------------------------------------------------------
// Host-side weight construction (runs at capture time; kernarg frozen into
// the graph). Replicates pywt/gaus1 exactly:
//   x = linspace(-5,5,1024); step = x[1]-x[0];
//   psi = -2x e^{-x^2}/(pi/2)^{1/4}; int_psi = cumsum(psi)*step (serial fp64)
//   j = (arange(10a+1)/(a*step)).astype(int64); f = f32(int_psi[j])
// Fused (conv + diff + trim): w_a[t] = -sqrt(a)*(f[t-1]-f[t]), f[-1]=f[L]=0.
// ---------------------------------------------------------------------------
extern "C" void kernel_launch(void* const* d_in, const int* in_sizes, int n_in,
                              void* d_out, int out_size, void* d_ws, size_t ws_size,
                              hipStream_t stream) {
  (void)n_in; (void)out_size; (void)d_ws; (void)ws_size;
  const float* x = (const float*)d_in[0];
  float* out = (float*)d_out;
  const int B = in_sizes[0] / (S_LEN * NCH);   // 32

  WtArgs W;
  {
    static double ip[1024];
    const double delta = 10.0 / 1023.0;
    const double step  = (-5.0 + delta) + 5.0;       // == numpy x[1]-x[0]
    const double cn    = pow(3.141592653589793 * 0.5, 0.25);
    double s = 0.0;
    for (int i = 0; i < 1024; ++i) {
      const double xi  = (i == 1023) ? 5.0 : ((double)i * delta - 5.0);
      const double psi = (-2.0 * xi) * exp(-(xi * xi)) / cn;
      s += psi;
      ip[i] = s * step;
    }
    const int   as_[3] = {6, 3, 1};
    const int   lf_[3] = {61, 31, 11};               // taps t = 0..lf
    float*      wp_[3] = {W.w6, W.w3, W.w1};
    for (int si = 0; si < 3; ++si) {
      const double denom = (double)as_[si] * step;
      const float  sqa   = (float)sqrt((double)as_[si]);
      const int    lf    = lf_[si];
      for (int t = 0; t <= lf; ++t) {
        float km1 = 0.f, kt = 0.f;
        if (t >= 1)      km1 = (float)ip[(long)(((double)(t - 1)) / denom)];
        if (t <= lf - 1) kt  = (float)ip[(long)(((double)t) / denom)];
        wp_[si][t] = -sqa * (km1 - kt);
      }
    }
  }

  const int nblk = (S_LEN / TILE_S) * B;       // 64 * 32 = 2048 (divisible by 8)
  dim3 grid(nblk);
  dim3 block(NCH, TY);                         // 512 threads = 8 waves
  hipLaunchKernelGGL(cwt_main, grid, block, 0, stream, x, out, W);
}

// Round 3
// 137.897 us; speedup vs baseline: 1.1978x; 1.1978x over previous
//
#include <hip/hip_runtime.h>
#include <math.h>

#define S_LEN  4096
#define NCH    64
#define TILE_S 64
#define NT     4           // s-tiles per block (pipelined)
#define RPT    8           // s-rows per thread
#define TY     8           // 512 threads = 8 waves
#define NQR    48          // ring quads (192 rows: 32-quad window + 16-quad prefetch)
#define NQS    49          // padded quad stride per channel (49%8==1 -> conflict-free)
#define WQ     18          // window quads per thread (72 rows >= 69 needed)
#define PQ     5           // preloaded quads (12-tap issue-to-use slack ~340cy)
#define WLEN   72          // win floats; used indices 1..69

// 106 fused filter taps, computed on HOST (fp64, bit-matching numpy's index
// math — validated earlier rounds, absmax 1.56e-2 vs 1.03e-1 threshold) and
// passed BY VALUE -> kernarg segment -> scalar s_load in kernel.
struct WtArgs { float w6[62]; float w3[32]; float w1[12]; };

// ---------------------------------------------------------------------------
// Round-6. R2 post-mortem: direct-global version is latency-bound (VALUBusy
// 19.5% = exactly the VALU floor smeared over 80us; 80% s_waitcnt). LDS halo
// sharing must come back, but the old LDS versions (~50us) lost 2x to (a) 69
// scalar ds_read_b32/thread and (b) bulk-sync phases (HBM idle in compute).
// This version:
//  * TRANSPOSED LDS lds[c][quad], quad stride 49 (odd) -> window reads are 18
//    ds_read_b128/thread, bank-group (c+slot)&7 conflict-free both sides.
//    Staging: lane=channel scalar-dword global loads (256B/wave coalesced,
//    wave-uniform row guards) -> ds_write_b128 transposed, conflict-free.
//  * RING pipeline: block owns NT=4 consecutive s-tiles; 48-quad ring (49KB,
//    3 blocks/CU). Per tile: issue next tile's 8 global loads -> compute
//    (~1900cy hides HBM lat) -> vmcnt -> ds_write -> ONE barrier. Halo staged
//    exactly once; HBM read stream overlaps compute (T3-min/T14 pattern).
// All win/acc indices compile-time via template recursion (round-3 lesson).
// ---------------------------------------------------------------------------

template <int T, int R>
struct FmaR {
  static __device__ __forceinline__ void run(const WtArgs& W, const float (&win)[WLEN],
                                             float (&a6)[RPT], float (&a3)[RPT],
                                             float (&a1)[RPT]) {
    a6[R] = fmaf(W.w6[T], win[T + R + 1], a6[R]);
    if constexpr (T >= 15 && T <= 46) a3[R] = fmaf(W.w3[T - 15], win[T + R + 1], a3[R]);
    if constexpr (T >= 25 && T <= 36) a1[R] = fmaf(W.w1[T - 25], win[T + R + 1], a1[R]);
    FmaR<T, R + 1>::run(W, win, a6, a3, a1);
  }
};
template <int T>
struct FmaR<T, RPT> {
  static __device__ __forceinline__ void run(const WtArgs&, const float (&)[WLEN],
                                             float (&)[RPT], float (&)[RPT], float (&)[RPT]) {}
};

// Load quad Q of this thread's window from the transposed ring: slot =
// (Q0+Q) mod 48 (Q0 uniform per wave/tile). colbase = &lds[c*NQS*4], 16B-aligned.
template <int Q>
static __device__ __forceinline__ void load_quad(const float* __restrict__ colbase, int Q0,
                                                 float (&win)[WLEN]) {
  int s = Q0 + Q; if (s >= NQR) s -= NQR;
  const float4 v = *(const float4*)(colbase + (s << 2));
  win[4 * Q + 0] = v.x; win[4 * Q + 1] = v.y; win[4 * Q + 2] = v.z; win[4 * Q + 3] = v.w;
}

template <int Q>
struct PreQ {
  static __device__ __forceinline__ void run(const float* __restrict__ colbase, int Q0,
                                             float (&win)[WLEN]) {
    load_quad<Q>(colbase, Q0, win);
    PreQ<Q + 1>::run(colbase, Q0, win);
  }
};
template <>
struct PreQ<PQ> {
  static __device__ __forceinline__ void run(const float* __restrict__, int, float (&)[WLEN]) {}
};

template <int T>
struct Step {
  static __device__ __forceinline__ void run(const float* __restrict__ colbase, int Q0,
                                             const WtArgs& W, float (&win)[WLEN],
                                             float (&a6)[RPT], float (&a3)[RPT],
                                             float (&a1)[RPT]) {
    if constexpr ((T % 4 == 0) && (T / 4 + PQ < WQ))
      load_quad<T / 4 + PQ>(colbase, Q0, win);
    FmaR<T, 0>::run(W, win, a6, a3, a1);
    Step<T + 1>::run(colbase, Q0, W, win, a6, a3, a1);
  }
};
template <>
struct Step<62> {
  static __device__ __forceinline__ void run(const float* __restrict__, int, const WtArgs&,
                                             float (&)[WLEN], float (&)[RPT],
                                             float (&)[RPT], float (&)[RPT]) {}
};

template <int R>
struct Store {
  static __device__ __forceinline__ void run(float* __restrict__ o1, float* __restrict__ o3,
                                             float* __restrict__ o6, const float (&a6)[RPT],
                                             const float (&a3)[RPT], const float (&a1)[RPT]) {
    o1[(size_t)R * NCH] = a1[R];
    o3[(size_t)R * NCH] = a3[R];
    o6[(size_t)R * NCH] = a6[R];
    Store<R + 1>::run(o1, o3, o6, a6, a3, a1);
  }
};
template <>
struct Store<RPT> {
  static __device__ __forceinline__ void run(float* __restrict__, float* __restrict__,
                                             float* __restrict__, const float (&)[RPT],
                                             const float (&)[RPT], const float (&)[RPT]) {}
};

template <int R>
struct Zero {
  static __device__ __forceinline__ void run(float (&a6)[RPT], float (&a3)[RPT], float (&a1)[RPT]) {
    a6[R] = 0.f; a3[R] = 0.f; a1[R] = 0.f;
    Zero<R + 1>::run(a6, a3, a1);
  }
};
template <>
struct Zero<RPT> {
  static __device__ __forceinline__ void run(float (&)[RPT], float (&)[RPT], float (&)[RPT]) {}
};

__global__ __launch_bounds__(512, 4)
void cwt_main(const float* __restrict__ x, float* __restrict__ out, const WtArgs W) {
  // transposed ring: channel-major, 49-quad stride, 48 live quads
  __shared__ __align__(16) float lds[NCH * NQS * 4];   // 50176 B -> 3 blocks/CU

  const int c  = threadIdx.x;         // 0..63 (lane = channel)
  const int ty = threadIdx.y;         // 0..7 (wave)

  // Bijective XCD swizzle (512 % 8 == 0): 64 consecutive logical blocks per
  // XCD -> neighbouring tile-groups (sharing halo rows in L2) co-XCD.
  const int hw = blockIdx.x;                  // 0..511
  const int wg = ((hw & 7) << 6) + (hw >> 3);
  const int gp = wg & 15;                     // 16 tile-groups per signal
  const int b  = wg >> 4;                     // 32 signals
  const int s0b = gp * (TILE_S * NT);         // block covers rows s0b..s0b+255
  const int ROW0 = s0b - 32;                  // staged rows start (quad-aligned)

  const float* __restrict__ xb = x + (size_t)b * S_LEN * NCH;
  const float* __restrict__ colbase = &lds[c * (NQS * 4)];

  // ---- prologue: stage quads 0..31 (tile-0 window, rows ROW0..ROW0+127)
  {
    float pg[4][4];
    #pragma unroll
    for (int k = 0; k < 4; ++k) {
      const int g = 4 * ty + k;
      #pragma unroll
      for (int j = 0; j < 4; ++j) {
        const int row = ROW0 + 4 * g + j;          // wave-uniform
        float v = 0.f;
        if ((unsigned)row < (unsigned)S_LEN) v = xb[(size_t)row * NCH + c];
        pg[k][j] = v;
      }
    }
    #pragma unroll
    for (int k = 0; k < 4; ++k) {
      const int g = 4 * ty + k;                    // slot == quad (no wrap yet)
      *(float4*)&lds[c * (NQS * 4) + (g << 2)] =
          make_float4(pg[k][0], pg[k][1], pg[k][2], pg[k][3]);
    }
  }
  __syncthreads();

  // ---- pipelined tile loop: stage(i+1) loads || compute(i) || ds_write || bar
  #pragma clang loop unroll(disable)
  for (int i = 0; i < NT; ++i) {
    // issue next tile's global loads EARLY (quads 32+16i .. 47+16i; 2/wave)
    float sg[2][4];
    if (i < NT - 1) {
      #pragma unroll
      for (int k = 0; k < 2; ++k) {
        const int g = 32 + 16 * i + 2 * ty + k;
        #pragma unroll
        for (int j = 0; j < 4; ++j) {
          const int row = ROW0 + 4 * g + j;        // wave-uniform
          float v = 0.f;
          if ((unsigned)row < (unsigned)S_LEN) v = xb[(size_t)row * NCH + c];
          sg[k][j] = v;
        }
      }
    }

    // compute tile i from the ring (reads quads 16i..16i+31 — disjoint from
    // this tile's staged writes 16i+32..16i+47, so one barrier/tile suffices)
    float win[WLEN];
    float a6[RPT], a3[RPT], a1[RPT];
    Zero<0>::run(a6, a3, a1);
    const int Q0 = 16 * i + 2 * ty;                // window start quad (global)
    PreQ<0>::run(colbase, Q0, win);
    Step<0>::run(colbase, Q0, W, win, a6, a3, a1);

    // stores: 64 lanes x 4B contiguous per row; planes: 0=s1, 1=s3, 2=s6
    const int srow = s0b + TILE_S * i + RPT * ty;
    float* o1 = out + (((size_t)b * 3 + 0) * S_LEN + srow) * NCH + c;
    float* o3 = out + (((size_t)b * 3 + 1) * S_LEN + srow) * NCH + c;
    float* o6 = out + (((size_t)b * 3 + 2) * S_LEN + srow) * NCH + c;
    Store<0>::run(o1, o3, o6, a6, a3, a1);

    // land the prefetched quads into the ring (vmcnt wait sits here, after
    // ~1900cy of compute -> HBM latency fully hidden)
    if (i < NT - 1) {
      #pragma unroll
      for (int k = 0; k < 2; ++k) {
        const int g = 32 + 16 * i + 2 * ty + k;
        const int s = (g < NQR) ? g : g - NQR;
        *(float4*)&lds[c * (NQS * 4) + (s << 2)] =
            make_float4(sg[k][0], sg[k][1], sg[k][2], sg[k][3]);
      }
    }
    __syncthreads();
  }
}

// ---------------------------------------------------------------------------
// Host-side weight construction (runs at capture time; kernarg frozen into
// the graph). Replicates pywt/gaus1 exactly:
//   x = linspace(-5,5,1024); step = x[1]-x[0];
//   psi = -2x e^{-x^2}/(pi/2)^{1/4}; int_psi = cumsum(psi)*step (serial fp64)
//   j = (arange(10a+1)/(a*step)).astype(int64); f = f32(int_psi[j])
// Fused (conv + diff + trim): w_a[t] = -sqrt(a)*(f[t-1]-f[t]), f[-1]=f[L]=0.
// ---------------------------------------------------------------------------
extern "C" void kernel_launch(void* const* d_in, const int* in_sizes, int n_in,
                              void* d_out, int out_size, void* d_ws, size_t ws_size,
                              hipStream_t stream) {
  (void)n_in; (void)out_size; (void)d_ws; (void)ws_size;
  const float* x = (const float*)d_in[0];
  float* out = (float*)d_out;
  const int B = in_sizes[0] / (S_LEN * NCH);   // 32

  WtArgs W;
  {
    static double ip[1024];
    const double delta = 10.0 / 1023.0;
    const double step  = (-5.0 + delta) + 5.0;       // == numpy x[1]-x[0]
    const double cn    = pow(3.141592653589793 * 0.5, 0.25);
    double s = 0.0;
    for (int i = 0; i < 1024; ++i) {
      const double xi  = (i == 1023) ? 5.0 : ((double)i * delta - 5.0);
      const double psi = (-2.0 * xi) * exp(-(xi * xi)) / cn;
      s += psi;
      ip[i] = s * step;
    }
    const int   as_[3] = {6, 3, 1};
    const int   lf_[3] = {61, 31, 11};               // taps t = 0..lf
    float*      wp_[3] = {W.w6, W.w3, W.w1};
    for (int si = 0; si < 3; ++si) {
      const double denom = (double)as_[si] * step;
      const float  sqa   = (float)sqrt((double)as_[si]);
      const int    lf    = lf_[si];
      for (int t = 0; t <= lf; ++t) {
        float km1 = 0.f, kt = 0.f;
        if (t >= 1)      km1 = (float)ip[(long)(((double)(t - 1)) / denom)];
        if (t <= lf - 1) kt  = (float)ip[(long)(((double)t) / denom)];
        wp_[si][t] = -sqa * (km1 - kt);
      }
    }
  }

  const int nblk = (S_LEN / (TILE_S * NT)) * B;  // 16 * 32 = 512 (div by 8)
  dim3 grid(nblk);
  dim3 block(NCH, TY);                           // 512 threads = 8 waves
  hipLaunchKernelGGL(cwt_main, grid, block, 0, stream, x, out, W);
}

// Round 4
// 130.518 us; speedup vs baseline: 1.2655x; 1.0565x over previous
//
#include <hip/hip_runtime.h>
#include <math.h>

#define S_LEN  4096
#define NCH    64
#define TILE_S 64
#define RPT    8           // s-rows per thread
#define TY     8           // 512 threads = 8 waves
#define NQ     32          // staged quads (128 rows = 64 tile + 64 halo)
#define NQS    33          // padded quad stride per channel (132 dw; 132%32=4 -> balanced)
#define WQ     18          // window quads per thread (72 rows >= 69 needed)
#define PQ     5           // preloaded quads (11-tap issue-to-use slack ~176cy)
#define WLEN   72          // win floats; used indices 1..69

// ---------------------------------------------------------------------------
// Round-7. R3 post-mortem: ring pipeline NULL (cwt ~53us, same as bulk-sync
// 50-53us across 3 structurally different LDS kernels; memory floor ~23us).
// The invariant suspect: 106 filter weights read from kernarg via s_load.
// s_load and ds_read SHARE lgkmcnt; 106 weights don't fit the SGPR file, so
// reloads interleave with window ds_reads and force coarse lgkm waits on the
// FMA stream in every variant. Fix: weights are pure compile-time constants
// (pywt gaus1, fixed spec) -> build with constexpr exp/sqrt, emit as VALU
// literals via template variables. ZERO s_load in the loop; lgkmcnt counts
// only the 18 ds_read_b128 -> compiler can emit precise per-quad lgkmcnt(N).
// Index math (the only bit-sensitive part) is identical double arithmetic to
// the validated host path; exp value differences ~1e-16 rel (threshold 6.6x
// headroom at absmax 1.56e-2 / 1.03e-1).
// Kept from R3: transposed quad LDS (ds_read_b128 x18, balanced bank groups).
// Reverted: ring/multi-tile (null). LDS 33KB -> 4 blocks/CU.
// ---------------------------------------------------------------------------

// ---- constexpr weight construction (compile-time) --------------------------
constexpr double cexp_(double v) {            // v in [-25, 0]
  const double LN2 = 0.6931471805599453;
  double t = v / LN2;
  int k = (int)t;
  if (t < 0.0 && (double)k != t) --k;
  double r = v - (double)k * LN2;             // r in [0, ln2)
  double term = 1.0, sum = 1.0;
  for (int n = 1; n <= 22; ++n) { term *= r / (double)n; sum += term; }
  while (k > 0) { sum *= 2.0; --k; }
  while (k < 0) { sum *= 0.5; ++k; }
  return sum;
}
constexpr double csqrt_(double a) {
  double y = a > 1.0 ? a : 1.0;
  for (int i = 0; i < 64; ++i) y = 0.5 * (y + a / y);
  return y;
}
struct Wt { float w6[62]; float w3[32]; float w1[12]; };
constexpr Wt make_weights() {
  Wt w{};
  double ip[1024] = {};
  const double delta = 10.0 / 1023.0;
  const double step  = (-5.0 + delta) + 5.0;        // == numpy x[1]-x[0]
  const double cn    = csqrt_(csqrt_(1.5707963267948966)); // (pi/2)^0.25
  double s = 0.0;
  for (int i = 0; i < 1024; ++i) {
    const double xi  = (i == 1023) ? 5.0 : ((double)i * delta - 5.0);
    const double psi = (-2.0 * xi) * cexp_(-(xi * xi)) / cn;
    s += psi;
    ip[i] = s * step;
  }
  const int as_[3] = {6, 3, 1};
  const int lf_[3] = {61, 31, 11};
  for (int si = 0; si < 3; ++si) {
    const double denom = (double)as_[si] * step;
    const float  sqa   = (float)csqrt_((double)as_[si]);
    const int    lf    = lf_[si];
    for (int t = 0; t <= lf; ++t) {
      float km1 = 0.f, kt = 0.f;
      if (t >= 1)      km1 = (float)ip[(long)(((double)(t - 1)) / denom)];
      if (t <= lf - 1) kt  = (float)ip[(long)(((double)t) / denom)];
      const float val = -sqa * (km1 - kt);
      if (si == 0) w.w6[t] = val; else if (si == 1) w.w3[t] = val; else w.w1[t] = val;
    }
  }
  return w;
}
constexpr Wt CW = make_weights();
// Template variables force compile-time folding -> inline literal operands.
template <int T> constexpr float W6 = CW.w6[T];
template <int T> constexpr float W3 = CW.w3[T];
template <int T> constexpr float W1 = CW.w1[T];

// ---- compute recursion (all indices compile-time) --------------------------
template <int T, int R>
struct FmaR {
  static __device__ __forceinline__ void run(const float (&win)[WLEN],
                                             float (&a6)[RPT], float (&a3)[RPT],
                                             float (&a1)[RPT]) {
    a6[R] = fmaf(W6<T>, win[T + R + 1], a6[R]);
    if constexpr (T >= 15 && T <= 46) a3[R] = fmaf(W3<T - 15>, win[T + R + 1], a3[R]);
    if constexpr (T >= 25 && T <= 36) a1[R] = fmaf(W1<T - 25>, win[T + R + 1], a1[R]);
    FmaR<T, R + 1>::run(win, a6, a3, a1);
  }
};
template <int T>
struct FmaR<T, RPT> {
  static __device__ __forceinline__ void run(const float (&)[WLEN],
                                             float (&)[RPT], float (&)[RPT], float (&)[RPT]) {}
};

// Load quad Q of this thread's window from the transposed LDS tile.
// colbase = &lds[c*NQS*4] (16B aligned); quad index = 2*ty + Q (compile-time Q).
template <int Q>
static __device__ __forceinline__ void load_quad(const float* __restrict__ colbase, int q0,
                                                 float (&win)[WLEN]) {
  const float4 v = *(const float4*)(colbase + ((q0 + Q) << 2));
  win[4 * Q + 0] = v.x; win[4 * Q + 1] = v.y; win[4 * Q + 2] = v.z; win[4 * Q + 3] = v.w;
}

template <int Q>
struct PreQ {
  static __device__ __forceinline__ void run(const float* __restrict__ colbase, int q0,
                                             float (&win)[WLEN]) {
    load_quad<Q>(colbase, q0, win);
    PreQ<Q + 1>::run(colbase, q0, win);
  }
};
template <>
struct PreQ<PQ> {
  static __device__ __forceinline__ void run(const float* __restrict__, int, float (&)[WLEN]) {}
};

template <int T>
struct Step {
  static __device__ __forceinline__ void run(const float* __restrict__ colbase, int q0,
                                             float (&win)[WLEN], float (&a6)[RPT],
                                             float (&a3)[RPT], float (&a1)[RPT]) {
    if constexpr ((T % 4 == 0) && (T / 4 + PQ < WQ))
      load_quad<T / 4 + PQ>(colbase, q0, win);
    FmaR<T, 0>::run(win, a6, a3, a1);
    Step<T + 1>::run(colbase, q0, win, a6, a3, a1);
  }
};
template <>
struct Step<62> {
  static __device__ __forceinline__ void run(const float* __restrict__, int, float (&)[WLEN],
                                             float (&)[RPT], float (&)[RPT], float (&)[RPT]) {}
};

template <int R>
struct Store {
  static __device__ __forceinline__ void run(float* __restrict__ o1, float* __restrict__ o3,
                                             float* __restrict__ o6, const float (&a6)[RPT],
                                             const float (&a3)[RPT], const float (&a1)[RPT]) {
    o1[(size_t)R * NCH] = a1[R];
    o3[(size_t)R * NCH] = a3[R];
    o6[(size_t)R * NCH] = a6[R];
    Store<R + 1>::run(o1, o3, o6, a6, a3, a1);
  }
};
template <>
struct Store<RPT> {
  static __device__ __forceinline__ void run(float* __restrict__, float* __restrict__,
                                             float* __restrict__, const float (&)[RPT],
                                             const float (&)[RPT], const float (&)[RPT]) {}
};

template <int R>
struct Zero {
  static __device__ __forceinline__ void run(float (&a6)[RPT], float (&a3)[RPT], float (&a1)[RPT]) {
    a6[R] = 0.f; a3[R] = 0.f; a1[R] = 0.f;
    Zero<R + 1>::run(a6, a3, a1);
  }
};
template <>
struct Zero<RPT> {
  static __device__ __forceinline__ void run(float (&)[RPT], float (&)[RPT], float (&)[RPT]) {}
};

__global__ __launch_bounds__(512, 6)
void cwt_main(const float* __restrict__ x, float* __restrict__ out) {
  // transposed tile: channel-major, 33-quad padded stride, 32 staged quads
  __shared__ __align__(16) float lds[NCH * NQS * 4];   // 33792 B -> 4 blocks/CU

  const int c  = threadIdx.x;         // 0..63 (lane = channel)
  const int ty = threadIdx.y;         // 0..7 (wave)

  // Bijective XCD swizzle (2048 % 8 == 0): 256 consecutive logical blocks per
  // XCD; consecutive sx tiles share 64 halo rows -> same-XCD L2 hits.
  const int hw = blockIdx.x;                  // 0..2047
  const int wg = ((hw & 7) << 8) + (hw >> 3);
  const int sx = wg & 63;                     // 64 s-tiles (fastest within XCD)
  const int b  = wg >> 6;                     // 32 signals
  const int s0 = sx * TILE_S;
  const int ROW0 = s0 - 32;                   // staged rows (quad-aligned halo)

  const float* __restrict__ xb = x + (size_t)b * S_LEN * NCH;

  // ---- stage 128 rows, transposed: lane=channel scalar loads (256B/wave,
  // coalesced), wave-uniform guards, then 4 ds_write_b128 per thread.
  {
    float pg[4][4];
    #pragma unroll
    for (int k = 0; k < 4; ++k) {
      #pragma unroll
      for (int j = 0; j < 4; ++j) {
        const int row = ROW0 + 16 * ty + 4 * k + j;   // wave-uniform
        float v = 0.f;
        if ((unsigned)row < (unsigned)S_LEN) v = xb[(size_t)row * NCH + c];
        pg[k][j] = v;
      }
    }
    #pragma unroll
    for (int k = 0; k < 4; ++k) {
      const int q = 4 * ty + k;
      *(float4*)&lds[c * (NQS * 4) + (q << 2)] =
          make_float4(pg[k][0], pg[k][1], pg[k][2], pg[k][3]);
    }
  }
  __syncthreads();

  // ---- sliding-window tap recursion; lgkmcnt traffic = ds_read_b128 ONLY
  const float* __restrict__ colbase = &lds[c * (NQS * 4)];
  const int q0 = 2 * ty;                      // thread's window start quad

  float win[WLEN];
  float a6[RPT], a3[RPT], a1[RPT];
  Zero<0>::run(a6, a3, a1);
  PreQ<0>::run(colbase, q0, win);             // quads 0..4 (20 rows)
  Step<0>::run(colbase, q0, win, a6, a3, a1); // taps 0..61, quad loads inline

  // ---- stores: 64 lanes x 4B contiguous per row; planes: 0=s1, 1=s3, 2=s6
  const int srow = s0 + RPT * ty;
  float* o1 = out + (((size_t)b * 3 + 0) * S_LEN + srow) * NCH + c;
  float* o3 = out + (((size_t)b * 3 + 1) * S_LEN + srow) * NCH + c;
  float* o6 = out + (((size_t)b * 3 + 2) * S_LEN + srow) * NCH + c;
  Store<0>::run(o1, o3, o6, a6, a3, a1);
}

extern "C" void kernel_launch(void* const* d_in, const int* in_sizes, int n_in,
                              void* d_out, int out_size, void* d_ws, size_t ws_size,
                              hipStream_t stream) {
  (void)n_in; (void)out_size; (void)d_ws; (void)ws_size;
  const float* x = (const float*)d_in[0];
  float* out = (float*)d_out;
  const int B = in_sizes[0] / (S_LEN * NCH);   // 32

  const int nblk = (S_LEN / TILE_S) * B;       // 64 * 32 = 2048 (div by 8)
  dim3 grid(nblk);
  dim3 block(NCH, TY);                         // 512 threads = 8 waves
  hipLaunchKernelGGL(cwt_main, grid, block, 0, stream, x, out);
}